// Round 2
// baseline (422.515 us; speedup 1.0000x reference)
//
#include <hip/hip_runtime.h>

#define B_SZ 8
#define L_SZ 1024
#define DM   256
#define ED   512
#define M_SZ (B_SZ * L_SZ)   // 8192

__device__ __forceinline__ float siluf(float x) { return x / (1.f + __expf(-x)); }
__device__ __forceinline__ float softplusf(float x) { return x > 20.f ? x : log1pf(__expf(x)); }

// cross-lane add via DPP (VALU pipe, not LDS pipe); ctrl must be compile-time
template<int CTRL>
__device__ __forceinline__ float dpp_add(float v) {
    int t = __builtin_amdgcn_update_dpp(0, __float_as_int(v), CTRL, 0xF, 0xF, true);
    return v + __int_as_float(t);
}

// C[i,j] = sum_k A[i,k]*B[j,k]  (both K-contiguous, "NT").
// Tile 128x64, Ktile 16, 256 threads, 8x4 per thread.
// SPLIT: K split across blockIdx.z, atomicAdd stores, N-guard (Nb).
template<bool SPLIT>
__global__ __launch_bounds__(256) void gemm_nt(const float* __restrict__ A, const float* __restrict__ Bm,
    float* __restrict__ C, int Klen, int lda, int ldb, int ldc, int Nb)
{
    __shared__ float As[16][132];  // [k][m], stride 132 -> 16B aligned rows, 2-way max conflicts
    __shared__ float Bs[16][68];   // [k][n]
    const int tid = threadIdx.x;
    const int i0 = blockIdx.y * 128;
    const int j0 = blockIdx.x * 64;
    const int kbase = SPLIT ? blockIdx.z * Klen : 0;
    const int tx = tid & 15, ty = tid >> 4;
    const int r  = tid >> 2;
    const int kc = (tid & 3) << 2;
    float acc[8][4] = {{0.f}};
    const float* Arow0 = A + (size_t)(i0 + r) * lda + kbase + kc;
    const float* Arow1 = Arow0 + (size_t)64 * lda;
    const float* Brow  = Bm + (size_t)(j0 + r) * ldb + kbase + kc;
    const bool bok = (!SPLIT) || (j0 + r < Nb);
    for (int k0 = 0; k0 < Klen; k0 += 16) {
        float4 va0 = *(const float4*)(Arow0 + k0);
        float4 va1 = *(const float4*)(Arow1 + k0);
        float4 vb  = bok ? *(const float4*)(Brow + k0) : make_float4(0.f,0.f,0.f,0.f);
        As[kc+0][r]    = va0.x; As[kc+1][r]    = va0.y; As[kc+2][r]    = va0.z; As[kc+3][r]    = va0.w;
        As[kc+0][64+r] = va1.x; As[kc+1][64+r] = va1.y; As[kc+2][64+r] = va1.z; As[kc+3][64+r] = va1.w;
        Bs[kc+0][r]    = vb.x;  Bs[kc+1][r]    = vb.y;  Bs[kc+2][r]    = vb.z;  Bs[kc+3][r]    = vb.w;
        __syncthreads();
        #pragma unroll
        for (int k = 0; k < 16; ++k) {
            float a[8], bb[4];
            *(float4*)&a[0] = *(const float4*)&As[k][ty*8];
            *(float4*)&a[4] = *(const float4*)&As[k][ty*8+4];
            *(float4*)&bb[0] = *(const float4*)&Bs[k][tx*4];
            #pragma unroll
            for (int ii = 0; ii < 8; ++ii)
                #pragma unroll
                for (int jj = 0; jj < 4; ++jj)
                    acc[ii][jj] = fmaf(a[ii], bb[jj], acc[ii][jj]);
        }
        __syncthreads();
    }
    if (!SPLIT) {
        #pragma unroll
        for (int ii = 0; ii < 8; ++ii) {
            float4 v = make_float4(acc[ii][0], acc[ii][1], acc[ii][2], acc[ii][3]);
            *(float4*)&C[(size_t)(i0 + ty*8 + ii) * ldc + j0 + tx*4] = v;
        }
    } else {
        #pragma unroll
        for (int ii = 0; ii < 8; ++ii)
            #pragma unroll
            for (int jj = 0; jj < 4; ++jj) {
                int col = j0 + tx*4 + jj;
                if (col < Nb)
                    atomicAdd(&C[(size_t)(i0 + ty*8 + ii) * ldc + col], acc[ii][jj]);
            }
    }
}

// causal depthwise conv(16) + bias + SiLU. xz row stride 1024 (f-half = cols 0..511).
// thread: 4 e's (float4), 64 l's, rolling 16-row register window.
__global__ __launch_bounds__(256) void conv_silu(const float* __restrict__ xz,
    const float* __restrict__ Wc, const float* __restrict__ bc, float* __restrict__ xf)
{
    int t  = blockIdx.x * 256 + threadIdx.x;     // 0..16383
    int e4 = (t & 127) * 4;
    int l0 = ((t >> 7) & 15) * 64;
    int b  = t >> 11;
    float4 w[16];
    #pragma unroll
    for (int k = 0; k < 16; ++k)
        w[k] = make_float4(Wc[(e4+0)*16+k], Wc[(e4+1)*16+k], Wc[(e4+2)*16+k], Wc[(e4+3)*16+k]);
    float4 bc4 = *(const float4*)&bc[e4];
    const float* xzb = xz + (size_t)b * L_SZ * 1024 + e4;
    float*       xfb = xf + (size_t)b * L_SZ * ED + e4;
    float4 xw[16];  // ring: slot (row & 15) holds row
    #pragma unroll
    for (int j = 1; j <= 15; ++j) {
        int row = l0 - 16 + j;
        xw[j] = (row >= 0) ? *(const float4*)(xzb + (size_t)row * 1024) : make_float4(0.f,0.f,0.f,0.f);
    }
    for (int ii = 0; ii < 4; ++ii) {
        #pragma unroll
        for (int u = 0; u < 16; ++u) {
            int l = l0 + ii*16 + u;
            xw[u] = *(const float4*)(xzb + (size_t)l * 1024);
            float4 acc = bc4;
            #pragma unroll
            for (int k = 0; k < 16; ++k) {
                float4 xv = xw[(u + k + 1) & 15];   // row l-15+k
                acc.x = fmaf(xv.x, w[k].x, acc.x);
                acc.y = fmaf(xv.y, w[k].y, acc.y);
                acc.z = fmaf(xv.z, w[k].z, acc.z);
                acc.w = fmaf(xv.w, w[k].w, acc.w);
            }
            float4 o = make_float4(siluf(acc.x), siluf(acc.y), siluf(acc.z), siluf(acc.w));
            *(float4*)(xfb + (size_t)l * ED) = o;
        }
    }
}

// delta[m,e] = softplus(sum_r dBC[m,r]*W_dt[e,r] + b_dt[e]); block: 32 rows, thread: e in {tid, tid+256}
__global__ __launch_bounds__(256) void delta_kernel(const float* __restrict__ dBC,
    const float* __restrict__ W_dt, const float* __restrict__ b_dt, float* __restrict__ dlt)
{
    const int tid = threadIdx.x;
    const int m0 = blockIdx.x * 32;
    float w0[16], w1[16];
    #pragma unroll
    for (int q = 0; q < 4; ++q) {
        *(float4*)&w0[q*4] = *(const float4*)&W_dt[(size_t)tid*16 + q*4];
        *(float4*)&w1[q*4] = *(const float4*)&W_dt[(size_t)(tid+256)*16 + q*4];
    }
    float bd0 = b_dt[tid], bd1 = b_dt[tid+256];
    for (int m = 0; m < 32; ++m) {
        const float* row = dBC + (size_t)(m0+m)*48;
        float qr[16];
        #pragma unroll
        for (int q = 0; q < 4; ++q) *(float4*)&qr[q*4] = *(const float4*)&row[q*4];
        float s0 = bd0, s1 = bd1;
        #pragma unroll
        for (int rr = 0; rr < 16; ++rr) { s0 = fmaf(qr[rr], w0[rr], s0); s1 = fmaf(qr[rr], w1[rr], s1); }
        dlt[(size_t)(m0+m)*512 + tid]       = softplusf(s0);
        dlt[(size_t)(m0+m)*512 + tid + 256] = softplusf(s1);
    }
}

// scan: thread = (n = tid&15, el = tid>>4); block = (b, 16 e's); DPP reduce over n.
__global__ __launch_bounds__(256) void scan_kernel(
    const float* __restrict__ dlt, const float* __restrict__ xf,
    const float* __restrict__ dbc, const float* __restrict__ A_log,
    const float* __restrict__ D, float* __restrict__ y)
{
    __shared__ float ds_d[16][68];   // [e][l]
    __shared__ float ds_x[16][68];
    __shared__ float ds_Bv[16][68];  // [n][l]
    __shared__ float ds_Cv[16][68];
    __shared__ float ds_y[16][68];
    const int tid = threadIdx.x;
    const int b  = blockIdx.x >> 5;
    const int e0 = (blockIdx.x & 31) << 4;
    const int n  = tid & 15;
    const int el = tid >> 4;
    const int e  = e0 + el;
    const float An = -__expf(A_log[e * 16 + n]);
    const float Dv = D[e];
    float h = 0.f;
    const size_t rowbase = (size_t)b * 1024;
    for (int l0 = 0; l0 < 1024; l0 += 64) {
        #pragma unroll
        for (int s = 0; s < 4; ++s) {
            int idx = tid + s * 256;
            int li = idx >> 4, ei = idx & 15;
            size_t row = rowbase + l0 + li;
            ds_d[ei][li]  = dlt[row * 512 + e0 + ei];
            ds_x[ei][li]  = xf [row * 512 + e0 + ei];
            ds_Bv[ei][li] = dbc[row * 48 + 16 + ei];
            ds_Cv[ei][li] = dbc[row * 48 + 32 + ei];
        }
        __syncthreads();
        for (int li4 = 0; li4 < 64; li4 += 4) {
            float4 dv = *(const float4*)&ds_d[el][li4];
            float4 xv = *(const float4*)&ds_x[el][li4];
            float4 bv = *(const float4*)&ds_Bv[n][li4];
            float4 cv = *(const float4*)&ds_Cv[n][li4];
            float yo[4];
            #pragma unroll
            for (int u = 0; u < 4; ++u) {
                float dd = (&dv.x)[u], xx = (&xv.x)[u], bb = (&bv.x)[u], cc = (&cv.x)[u];
                float dA = __expf(dd * An);
                h = fmaf(dA, h, dd * bb * xx);
                float p = h * cc;
                p = dpp_add<0xB1>(p);   // quad_perm xor1
                p = dpp_add<0x4E>(p);   // quad_perm xor2
                p = dpp_add<0x141>(p);  // row_half_mirror (xor4... pairs within 8)
                p = dpp_add<0x140>(p);  // row_mirror -> 16-lane sum
                yo[u] = fmaf(Dv, xx, p);
            }
            if (n == 0) *(float4*)&ds_y[el][li4] = make_float4(yo[0], yo[1], yo[2], yo[3]);
        }
        __syncthreads();
        #pragma unroll
        for (int s = 0; s < 4; ++s) {
            int idx = tid + s * 256;
            int li = idx >> 4, ei = idx & 15;
            size_t row = rowbase + l0 + li;
            y[row * 512 + e0 + ei] = ds_y[ei][li];
        }
    }
}

// g = y * silu(zf), zf = xz[:, 512:1024]
__global__ __launch_bounds__(256) void gate_kernel(const float* __restrict__ y,
    const float* __restrict__ xz, float* __restrict__ g)
{
    int i  = blockIdx.x * 256 + threadIdx.x;  // float4 index
    int i4 = i * 4;
    int m  = i4 >> 9;
    int e  = i4 & 511;
    float4 yv = *(const float4*)&y[i4];
    float4 zv = *(const float4*)&xz[(size_t)m * 1024 + 512 + e];
    float4 o = make_float4(yv.x * siluf(zv.x), yv.y * siluf(zv.y),
                           yv.z * siluf(zv.z), yv.w * siluf(zv.w));
    *(float4*)&g[i4] = o;
}

extern "C" void kernel_launch(void* const* d_in, const int* in_sizes, int n_in,
                              void* d_out, int out_size, void* d_ws, size_t ws_size,
                              hipStream_t stream) {
    const float* x      = (const float*)d_in[0];
    const float* W_in   = (const float*)d_in[1];
    const float* W_conv = (const float*)d_in[2];
    const float* b_conv = (const float*)d_in[3];
    const float* W_x    = (const float*)d_in[4];
    const float* W_dt   = (const float*)d_in[5];
    const float* b_dt   = (const float*)d_in[6];
    const float* A_log  = (const float*)d_in[7];
    const float* D      = (const float*)d_in[8];
    const float* W_out  = (const float*)d_in[9];
    float* out = (float*)d_out;

    float* ws  = (float*)d_ws;
    float* xz  = ws;                            // 8192*1024
    float* xf  = xz  + (size_t)M_SZ * 1024;     // 8192*512
    float* dbc = xf  + (size_t)M_SZ * ED;       // 8192*48
    float* dlt = dbc + (size_t)M_SZ * 48;       // 8192*512
    float* yb  = dlt + (size_t)M_SZ * ED;       // 8192*512
    float* g   = dlt;                            // reuse (dlt consumed by scan)

    // 1) xz = x @ W_in^T   (8192x1024, K=256)
    gemm_nt<false><<<dim3(16, 64, 1), 256, 0, stream>>>(x, W_in, xz, 256, 256, 256, 1024, 1024);
    // 2) xf = silu(causal_conv(xz[:, :512]) + b_conv)
    conv_silu<<<64, 256, 0, stream>>>(xz, W_conv, b_conv, xf);
    // 3) dBC = xf @ W_x^T  (8192x48, K=512), split-K=4 with atomics
    (void)hipMemsetAsync(dbc, 0, (size_t)M_SZ * 48 * sizeof(float), stream);
    gemm_nt<true><<<dim3(1, 64, 4), 256, 0, stream>>>(xf, W_x, dbc, 128, 512, 512, 48, 48);
    // 4) delta = softplus(dBC[:, :16] @ W_dt^T + b_dt)
    delta_kernel<<<256, 256, 0, stream>>>(dbc, W_dt, b_dt, dlt);
    // 5) selective scan -> yb (includes + D*xf)
    scan_kernel<<<256, 256, 0, stream>>>(dlt, xf, dbc, A_log, D, yb);
    // 6) g = yb * silu(zf)
    gate_kernel<<<4096, 256, 0, stream>>>(yb, xz, g);
    // 7) out = g @ W_out^T (8192x256, K=512)
    gemm_nt<false><<<dim3(4, 64, 1), 256, 0, stream>>>(g, W_out, out, 512, 512, 512, 256, 256);
}

// Round 3
// 345.123 us; speedup vs baseline: 1.2242x; 1.2242x over previous
//
#include <hip/hip_runtime.h>

#define B_SZ 8
#define L_SZ 1024
#define DM   256
#define ED   512
#define M_SZ (B_SZ * L_SZ)   // 8192
#define CH   16              // scan chunks
#define LC   64              // chunk length

__device__ __forceinline__ float siluf(float x) { return x / (1.f + __expf(-x)); }
__device__ __forceinline__ float softplusf(float x) { return x > 20.f ? x : log1pf(__expf(x)); }

// cross-lane add via DPP (VALU pipe, not LDS pipe); ctrl must be compile-time
template<int CTRL>
__device__ __forceinline__ float dpp_add(float v) {
    int t = __builtin_amdgcn_update_dpp(0, __float_as_int(v), CTRL, 0xF, 0xF, true);
    return v + __int_as_float(t);
}

// C[i,j] = sum_k A[i,k]*B[j,k]  (both K-contiguous, "NT").
// Tile 128x64, Ktile 16, 256 threads, 8x4 per thread.
// SPLIT: K split across blockIdx.z, atomicAdd stores, N-guard (Nb).
template<bool SPLIT>
__global__ __launch_bounds__(256) void gemm_nt(const float* __restrict__ A, const float* __restrict__ Bm,
    float* __restrict__ C, int Klen, int lda, int ldb, int ldc, int Nb)
{
    __shared__ float As[16][132];
    __shared__ float Bs[16][68];
    const int tid = threadIdx.x;
    const int i0 = blockIdx.y * 128;
    const int j0 = blockIdx.x * 64;
    const int kbase = SPLIT ? blockIdx.z * Klen : 0;
    const int tx = tid & 15, ty = tid >> 4;
    const int r  = tid >> 2;
    const int kc = (tid & 3) << 2;
    float acc[8][4] = {{0.f}};
    const float* Arow0 = A + (size_t)(i0 + r) * lda + kbase + kc;
    const float* Arow1 = Arow0 + (size_t)64 * lda;
    const float* Brow  = Bm + (size_t)(j0 + r) * ldb + kbase + kc;
    const bool bok = (!SPLIT) || (j0 + r < Nb);
    for (int k0 = 0; k0 < Klen; k0 += 16) {
        float4 va0 = *(const float4*)(Arow0 + k0);
        float4 va1 = *(const float4*)(Arow1 + k0);
        float4 vb  = bok ? *(const float4*)(Brow + k0) : make_float4(0.f,0.f,0.f,0.f);
        As[kc+0][r]    = va0.x; As[kc+1][r]    = va0.y; As[kc+2][r]    = va0.z; As[kc+3][r]    = va0.w;
        As[kc+0][64+r] = va1.x; As[kc+1][64+r] = va1.y; As[kc+2][64+r] = va1.z; As[kc+3][64+r] = va1.w;
        Bs[kc+0][r]    = vb.x;  Bs[kc+1][r]    = vb.y;  Bs[kc+2][r]    = vb.z;  Bs[kc+3][r]    = vb.w;
        __syncthreads();
        #pragma unroll
        for (int k = 0; k < 16; ++k) {
            float a[8], bb[4];
            *(float4*)&a[0] = *(const float4*)&As[k][ty*8];
            *(float4*)&a[4] = *(const float4*)&As[k][ty*8+4];
            *(float4*)&bb[0] = *(const float4*)&Bs[k][tx*4];
            #pragma unroll
            for (int ii = 0; ii < 8; ++ii)
                #pragma unroll
                for (int jj = 0; jj < 4; ++jj)
                    acc[ii][jj] = fmaf(a[ii], bb[jj], acc[ii][jj]);
        }
        __syncthreads();
    }
    if (!SPLIT) {
        #pragma unroll
        for (int ii = 0; ii < 8; ++ii) {
            float4 v = make_float4(acc[ii][0], acc[ii][1], acc[ii][2], acc[ii][3]);
            *(float4*)&C[(size_t)(i0 + ty*8 + ii) * ldc + j0 + tx*4] = v;
        }
    } else {
        #pragma unroll
        for (int ii = 0; ii < 8; ++ii)
            #pragma unroll
            for (int jj = 0; jj < 4; ++jj) {
                int col = j0 + tx*4 + jj;
                if (col < Nb)
                    atomicAdd(&C[(size_t)(i0 + ty*8 + ii) * ldc + col], acc[ii][jj]);
            }
    }
}

// causal depthwise conv(16) + bias + SiLU
__global__ __launch_bounds__(256) void conv_silu(const float* __restrict__ xz,
    const float* __restrict__ Wc, const float* __restrict__ bc, float* __restrict__ xf)
{
    int t  = blockIdx.x * 256 + threadIdx.x;
    int e4 = (t & 127) * 4;
    int l0 = ((t >> 7) & 15) * 64;
    int b  = t >> 11;
    float4 w[16];
    #pragma unroll
    for (int k = 0; k < 16; ++k)
        w[k] = make_float4(Wc[(e4+0)*16+k], Wc[(e4+1)*16+k], Wc[(e4+2)*16+k], Wc[(e4+3)*16+k]);
    float4 bc4 = *(const float4*)&bc[e4];
    const float* xzb = xz + (size_t)b * L_SZ * 1024 + e4;
    float*       xfb = xf + (size_t)b * L_SZ * ED + e4;
    float4 xw[16];
    #pragma unroll
    for (int j = 1; j <= 15; ++j) {
        int row = l0 - 16 + j;
        xw[j] = (row >= 0) ? *(const float4*)(xzb + (size_t)row * 1024) : make_float4(0.f,0.f,0.f,0.f);
    }
    for (int ii = 0; ii < 4; ++ii) {
        #pragma unroll
        for (int u = 0; u < 16; ++u) {
            int l = l0 + ii*16 + u;
            xw[u] = *(const float4*)(xzb + (size_t)l * 1024);
            float4 acc = bc4;
            #pragma unroll
            for (int k = 0; k < 16; ++k) {
                float4 xv = xw[(u + k + 1) & 15];
                acc.x = fmaf(xv.x, w[k].x, acc.x);
                acc.y = fmaf(xv.y, w[k].y, acc.y);
                acc.z = fmaf(xv.z, w[k].z, acc.z);
                acc.w = fmaf(xv.w, w[k].w, acc.w);
            }
            float4 o = make_float4(siluf(acc.x), siluf(acc.y), siluf(acc.z), siluf(acc.w));
            *(float4*)(xfb + (size_t)l * ED) = o;
        }
    }
}

// delta[m,e] = softplus(sum_r dBC[m,r]*W_dt[e,r] + b_dt[e])
__global__ __launch_bounds__(256) void delta_kernel(const float* __restrict__ dBC,
    const float* __restrict__ W_dt, const float* __restrict__ b_dt, float* __restrict__ dlt)
{
    const int tid = threadIdx.x;
    const int m0 = blockIdx.x * 32;
    float w0[16], w1[16];
    #pragma unroll
    for (int q = 0; q < 4; ++q) {
        *(float4*)&w0[q*4] = *(const float4*)&W_dt[(size_t)tid*16 + q*4];
        *(float4*)&w1[q*4] = *(const float4*)&W_dt[(size_t)(tid+256)*16 + q*4];
    }
    float bd0 = b_dt[tid], bd1 = b_dt[tid+256];
    for (int m = 0; m < 32; ++m) {
        const float* row = dBC + (size_t)(m0+m)*48;
        float qr[16];
        #pragma unroll
        for (int q = 0; q < 4; ++q) *(float4*)&qr[q*4] = *(const float4*)&row[q*4];
        float s0 = bd0, s1 = bd1;
        #pragma unroll
        for (int rr = 0; rr < 16; ++rr) { s0 = fmaf(qr[rr], w0[rr], s0); s1 = fmaf(qr[rr], w1[rr], s1); }
        dlt[(size_t)(m0+m)*512 + tid]       = softplusf(s0);
        dlt[(size_t)(m0+m)*512 + tid + 256] = softplusf(s1);
    }
}

// ---------- chunked scan ----------
// pass 1: per (b, egroup, chunk): local scan with h0=0 -> hend, running decay product -> pprod
// layout of hend/pprod/hs: [b][c][e][n]  (= (b*16+c)*8192 + e*16 + n)
__global__ __launch_bounds__(256) void scan_local(
    const float* __restrict__ dlt, const float* __restrict__ xf,
    const float* __restrict__ dbc, const float* __restrict__ A_log,
    float* __restrict__ hend, float* __restrict__ pprod)
{
    __shared__ float ds_d[16][68];   // [e][l]
    __shared__ float ds_x[16][68];
    __shared__ float ds_Bv[16][68];  // [n][l]
    const int tid = threadIdx.x;
    const int blk = blockIdx.x;              // ((b*32+eg)*16 + c)
    const int c  = blk & 15;
    const int eg = (blk >> 4) & 31;
    const int b  = blk >> 9;
    const int e0 = eg << 4;
    const int n  = tid & 15;
    const float An = -__expf(A_log[e0 * 16 + tid]);  // (e0+el)*16+n
    const int el = tid >> 4;
    const size_t rowbase = (size_t)b * 1024 + c * LC;
    #pragma unroll
    for (int s = 0; s < 4; ++s) {
        int idx = tid + s * 256;
        int li = idx >> 4, ei = idx & 15;
        size_t row = rowbase + li;
        ds_d[ei][li]  = dlt[row * 512 + e0 + ei];
        ds_x[ei][li]  = xf [row * 512 + e0 + ei];
        ds_Bv[ei][li] = dbc[row * 48 + 16 + ei];
    }
    __syncthreads();
    float h = 0.f, pd = 1.f;
    for (int li4 = 0; li4 < LC; li4 += 4) {
        float4 dv = *(const float4*)&ds_d[el][li4];
        float4 xv = *(const float4*)&ds_x[el][li4];
        float4 bv = *(const float4*)&ds_Bv[n][li4];
        #pragma unroll
        for (int u = 0; u < 4; ++u) {
            float dd = (&dv.x)[u], xx = (&xv.x)[u], bb = (&bv.x)[u];
            float dA = __expf(dd * An);
            h = fmaf(dA, h, dd * bb * xx);
            pd *= dA;
        }
    }
    size_t o = (size_t)(b * 16 + c) * 8192 + e0 * 16 + tid;
    hend[o]  = h;
    pprod[o] = pd;
}

// pass 2: sequential combine over chunks; thread = (b,e,n)
__global__ __launch_bounds__(256) void scan_prefix(
    const float* __restrict__ hend, const float* __restrict__ pprod, float* __restrict__ hs)
{
    int idx = blockIdx.x * 256 + threadIdx.x;   // 0..65535
    int b  = idx >> 13;
    int en = idx & 8191;
    size_t base = (size_t)b * 16 * 8192 + en;
    float h = 0.f;
    #pragma unroll
    for (int c = 0; c < 16; ++c) {
        size_t o = base + (size_t)c * 8192;
        hs[o] = h;
        h = fmaf(pprod[o], h, hend[o]);
    }
}

// pass 3: re-scan each chunk from hs, emit y (+ D*xf) with DPP n-reduce
__global__ __launch_bounds__(256) void scan_emit(
    const float* __restrict__ dlt, const float* __restrict__ xf,
    const float* __restrict__ dbc, const float* __restrict__ A_log,
    const float* __restrict__ D, const float* __restrict__ hs, float* __restrict__ y)
{
    __shared__ float ds_d[16][68];
    __shared__ float ds_x[16][68];
    __shared__ float ds_Bv[16][68];
    __shared__ float ds_Cv[16][68];
    __shared__ float ds_y[16][68];
    const int tid = threadIdx.x;
    const int blk = blockIdx.x;
    const int c  = blk & 15;
    const int eg = (blk >> 4) & 31;
    const int b  = blk >> 9;
    const int e0 = eg << 4;
    const int n  = tid & 15;
    const int el = tid >> 4;
    const float An = -__expf(A_log[e0 * 16 + tid]);
    const float Dv = D[e0 + el];
    const size_t rowbase = (size_t)b * 1024 + c * LC;
    #pragma unroll
    for (int s = 0; s < 4; ++s) {
        int idx = tid + s * 256;
        int li = idx >> 4, ei = idx & 15;
        size_t row = rowbase + li;
        ds_d[ei][li]  = dlt[row * 512 + e0 + ei];
        ds_x[ei][li]  = xf [row * 512 + e0 + ei];
        ds_Bv[ei][li] = dbc[row * 48 + 16 + ei];
        ds_Cv[ei][li] = dbc[row * 48 + 32 + ei];
    }
    float h = hs[(size_t)(b * 16 + c) * 8192 + e0 * 16 + tid];
    __syncthreads();
    for (int li4 = 0; li4 < LC; li4 += 4) {
        float4 dv = *(const float4*)&ds_d[el][li4];
        float4 xv = *(const float4*)&ds_x[el][li4];
        float4 bv = *(const float4*)&ds_Bv[n][li4];
        float4 cv = *(const float4*)&ds_Cv[n][li4];
        float yo[4];
        #pragma unroll
        for (int u = 0; u < 4; ++u) {
            float dd = (&dv.x)[u], xx = (&xv.x)[u], bb = (&bv.x)[u], cc = (&cv.x)[u];
            float dA = __expf(dd * An);
            h = fmaf(dA, h, dd * bb * xx);
            float p = h * cc;
            p = dpp_add<0xB1>(p);
            p = dpp_add<0x4E>(p);
            p = dpp_add<0x141>(p);
            p = dpp_add<0x140>(p);
            yo[u] = fmaf(Dv, xx, p);
        }
        if (n == 0) *(float4*)&ds_y[el][li4] = make_float4(yo[0], yo[1], yo[2], yo[3]);
    }
    __syncthreads();
    #pragma unroll
    for (int s = 0; s < 4; ++s) {
        int idx = tid + s * 256;
        int li = idx >> 4, ei = idx & 15;
        size_t row = rowbase + li;
        y[row * 512 + e0 + ei] = ds_y[ei][li];
    }
}

// g = y * silu(zf)
__global__ __launch_bounds__(256) void gate_kernel(const float* __restrict__ y,
    const float* __restrict__ xz, float* __restrict__ g)
{
    int i  = blockIdx.x * 256 + threadIdx.x;
    int i4 = i * 4;
    int m  = i4 >> 9;
    int e  = i4 & 511;
    float4 yv = *(const float4*)&y[i4];
    float4 zv = *(const float4*)&xz[(size_t)m * 1024 + 512 + e];
    float4 o = make_float4(yv.x * siluf(zv.x), yv.y * siluf(zv.y),
                           yv.z * siluf(zv.z), yv.w * siluf(zv.w));
    *(float4*)&g[i4] = o;
}

extern "C" void kernel_launch(void* const* d_in, const int* in_sizes, int n_in,
                              void* d_out, int out_size, void* d_ws, size_t ws_size,
                              hipStream_t stream) {
    const float* x      = (const float*)d_in[0];
    const float* W_in   = (const float*)d_in[1];
    const float* W_conv = (const float*)d_in[2];
    const float* b_conv = (const float*)d_in[3];
    const float* W_x    = (const float*)d_in[4];
    const float* W_dt   = (const float*)d_in[5];
    const float* b_dt   = (const float*)d_in[6];
    const float* A_log  = (const float*)d_in[7];
    const float* D      = (const float*)d_in[8];
    const float* W_out  = (const float*)d_in[9];
    float* out = (float*)d_out;

    float* ws   = (float*)d_ws;
    float* xz   = ws;                              // 8192*1024
    float* xf   = xz   + (size_t)M_SZ * 1024;      // 8192*512
    float* dbc  = xf   + (size_t)M_SZ * ED;        // 8192*48
    float* dlt  = dbc  + (size_t)M_SZ * 48;        // 8192*512
    float* yb   = dlt  + (size_t)M_SZ * ED;        // 8192*512
    float* hend = yb   + (size_t)M_SZ * ED;        // 8*16*8192 = 1M
    float* ppr  = hend + (size_t)B_SZ * CH * 8192; // 1M
    float* hs   = ppr  + (size_t)B_SZ * CH * 8192; // 1M
    float* g    = dlt;                             // reuse (dlt consumed by scan)

    // 1) xz = x @ W_in^T
    gemm_nt<false><<<dim3(16, 64, 1), 256, 0, stream>>>(x, W_in, xz, 256, 256, 256, 1024, 1024);
    // 2) xf = silu(causal_conv(xz[:, :512]) + b_conv)
    conv_silu<<<64, 256, 0, stream>>>(xz, W_conv, b_conv, xf);
    // 3) dBC = xf @ W_x^T, split-K=4
    (void)hipMemsetAsync(dbc, 0, (size_t)M_SZ * 48 * sizeof(float), stream);
    gemm_nt<true><<<dim3(1, 64, 4), 256, 0, stream>>>(xf, W_x, dbc, 128, 512, 512, 48, 48);
    // 4) delta
    delta_kernel<<<256, 256, 0, stream>>>(dbc, W_dt, b_dt, dlt);
    // 5) chunked selective scan
    scan_local <<<4096, 256, 0, stream>>>(dlt, xf, dbc, A_log, hend, ppr);
    scan_prefix<<<256, 256, 0, stream>>>(hend, ppr, hs);
    scan_emit  <<<4096, 256, 0, stream>>>(dlt, xf, dbc, A_log, D, hs, yb);
    // 6) g = yb * silu(zf)
    gate_kernel<<<4096, 256, 0, stream>>>(yb, xz, g);
    // 7) out = g @ W_out^T
    gemm_nt<false><<<dim3(4, 64, 1), 256, 0, stream>>>(g, W_out, out, 512, 512, 512, 256, 256);
}

// Round 6
// 279.852 us; speedup vs baseline: 1.5098x; 1.2332x over previous
//
#include <hip/hip_runtime.h>

#define B_SZ 8
#define L_SZ 1024
#define DM   256
#define ED   512
#define M_SZ (B_SZ * L_SZ)   // 8192
#define CH   16              // scan chunks
#define LC   64              // chunk length

typedef __attribute__((ext_vector_type(8))) short short8;
typedef __attribute__((ext_vector_type(4))) float floatx4;

__device__ __forceinline__ float siluf(float x) { return x / (1.f + __expf(-x)); }
__device__ __forceinline__ float softplusf(float x) { return x > 20.f ? x : log1pf(__expf(x)); }

template<int CTRL>
__device__ __forceinline__ float dpp_add(float v) {
    int t = __builtin_amdgcn_update_dpp(0, __float_as_int(v), CTRL, 0xF, 0xF, true);
    return v + __int_as_float(t);
}

__device__ __forceinline__ unsigned short f2bf(float f) {
    unsigned u = __float_as_uint(f);
    u += 0x7FFF + ((u >> 16) & 1);   // RNE
    return (unsigned short)(u >> 16);
}
__device__ __forceinline__ float bf2f(unsigned short h) {
    return __uint_as_float((unsigned)h << 16);
}

__device__ __forceinline__ void glds16(const unsigned short* g, unsigned short* l) {
    __builtin_amdgcn_global_load_lds(
        (const __attribute__((address_space(1))) void*)g,
        (__attribute__((address_space(3))) void*)l, 16, 0, 0);
}

// ---------------- split fp32 -> 3-segment bf16, row stride 3K ----------------
// A-side (BSIDE=false): [hi | lo | hi]
// B-side (BSIDE=true) : [hi | hi | lo]
// so A'.B' = hi*hi + lo*hi + hi*lo  (the correct split-bf16 product)
template<bool BSIDE>
__global__ __launch_bounds__(256) void split3(const float* __restrict__ S,
    unsigned short* __restrict__ Dst, int Klog2)
{
    int i  = blockIdx.x * 256 + threadIdx.x;
    int i4 = i << 2;
    int K  = 1 << Klog2;
    int row = i4 >> Klog2;
    int k   = i4 & (K - 1);
    float4 v = *(const float4*)&S[i4];
    ushort4 hi, lo;
    float f;
    f = v.x; hi.x = f2bf(f); lo.x = f2bf(f - bf2f(hi.x));
    f = v.y; hi.y = f2bf(f); lo.y = f2bf(f - bf2f(hi.y));
    f = v.z; hi.z = f2bf(f); lo.z = f2bf(f - bf2f(hi.z));
    f = v.w; hi.w = f2bf(f); lo.w = f2bf(f - bf2f(hi.w));
    size_t base = (size_t)row * (3 << Klog2) + k;
    *(ushort4*)&Dst[base] = hi;
    if (BSIDE) {
        *(ushort4*)&Dst[base + K]   = hi;
        *(ushort4*)&Dst[base + 2*K] = lo;
    } else {
        *(ushort4*)&Dst[base + K]   = lo;
        *(ushort4*)&Dst[base + 2*K] = hi;
    }
}

// ---------------- bf16 MFMA GEMM: C[M,N] = A'[M,K3] * B'[N,K3]^T ----------------
// 128x128 tile, BK=64, 4 waves (2x2 of 64x64), 16x16x32 bf16 MFMA, glds staging.
template<bool SPLITK>
__global__ __launch_bounds__(256) void gemm_bf16(
    const unsigned short* __restrict__ A, const unsigned short* __restrict__ Bm,
    float* __restrict__ C, int K3, int Klen, int ldc)
{
    __shared__ __align__(16) unsigned short As[128 * 64];
    __shared__ __align__(16) unsigned short Bs[128 * 64];
    const int tid = threadIdx.x;
    const int w  = tid >> 6, ln = tid & 63;
    const int m0 = blockIdx.y * 128, n0 = blockIdx.x * 128;
    const int kbase = SPLITK ? blockIdx.z * Klen : 0;
    const int lm = ln & 15, kg = ln >> 4;
    const int rb = (w >> 1) * 64, cb = (w & 1) * 64;
    floatx4 acc[4][4];
    #pragma unroll
    for (int i = 0; i < 4; ++i)
        #pragma unroll
        for (int j = 0; j < 4; ++j) acc[i][j] = (floatx4)0.f;

    const int srow = ln >> 3;          // 0..7
    const int scol = (ln & 7) * 8;     // bf16 col within BK
    const unsigned short* Ag = A  + (size_t)(m0 + w*32 + srow) * K3 + kbase + scol;
    const unsigned short* Bg = Bm + (size_t)(n0 + w*32 + srow) * K3 + kbase + scol;
    unsigned short* Al = &As[(w*32) * 64];   // wave-uniform LDS base
    unsigned short* Bl = &Bs[(w*32) * 64];

    for (int k0 = 0; k0 < Klen; k0 += 64) {
        #pragma unroll
        for (int q = 0; q < 4; ++q) {
            glds16(Ag + (size_t)(q*8) * K3 + k0, Al + (q*8) * 64);
            glds16(Bg + (size_t)(q*8) * K3 + k0, Bl + (q*8) * 64);
        }
        __syncthreads();
        #pragma unroll
        for (int kk = 0; kk < 64; kk += 32) {
            short8 af[4], bfr[4];
            #pragma unroll
            for (int i = 0; i < 4; ++i)
                af[i] = *(const short8*)&As[(rb + i*16 + lm) * 64 + kk + kg*8];
            #pragma unroll
            for (int j = 0; j < 4; ++j)
                bfr[j] = *(const short8*)&Bs[(cb + j*16 + lm) * 64 + kk + kg*8];
            #pragma unroll
            for (int i = 0; i < 4; ++i)
                #pragma unroll
                for (int j = 0; j < 4; ++j)
                    acc[i][j] = __builtin_amdgcn_mfma_f32_16x16x32_bf16(af[i], bfr[j], acc[i][j], 0, 0, 0);
        }
        __syncthreads();
    }
    #pragma unroll
    for (int i = 0; i < 4; ++i)
        #pragma unroll
        for (int j = 0; j < 4; ++j) {
            int row = m0 + rb + i*16 + kg*4;
            int col = n0 + cb + j*16 + lm;
            #pragma unroll
            for (int r = 0; r < 4; ++r) {
                float v = acc[i][j][r];
                if (SPLITK) atomicAdd(&C[(size_t)(row + r) * ldc + col], v);
                else        C[(size_t)(row + r) * ldc + col] = v;
            }
        }
}

// ---------------- fp32 NT GEMM (kept for the skinny dBC matmul) ----------------
template<bool SPLIT>
__global__ __launch_bounds__(256) void gemm_nt(const float* __restrict__ A, const float* __restrict__ Bm,
    float* __restrict__ C, int Klen, int lda, int ldb, int ldc, int Nb)
{
    __shared__ float Asf[16][132];
    __shared__ float Bsf[16][68];
    const int tid = threadIdx.x;
    const int i0 = blockIdx.y * 128;
    const int j0 = blockIdx.x * 64;
    const int kbase = SPLIT ? blockIdx.z * Klen : 0;
    const int tx = tid & 15, ty = tid >> 4;
    const int r  = tid >> 2;
    const int kc = (tid & 3) << 2;
    float acc[8][4] = {{0.f}};
    const float* Arow0 = A + (size_t)(i0 + r) * lda + kbase + kc;
    const float* Arow1 = Arow0 + (size_t)64 * lda;
    const float* Brow  = Bm + (size_t)(j0 + r) * ldb + kbase + kc;
    const bool bok = (!SPLIT) || (j0 + r < Nb);
    for (int k0 = 0; k0 < Klen; k0 += 16) {
        float4 va0 = *(const float4*)(Arow0 + k0);
        float4 va1 = *(const float4*)(Arow1 + k0);
        float4 vb  = bok ? *(const float4*)(Brow + k0) : make_float4(0.f,0.f,0.f,0.f);
        Asf[kc+0][r]    = va0.x; Asf[kc+1][r]    = va0.y; Asf[kc+2][r]    = va0.z; Asf[kc+3][r]    = va0.w;
        Asf[kc+0][64+r] = va1.x; Asf[kc+1][64+r] = va1.y; Asf[kc+2][64+r] = va1.z; Asf[kc+3][64+r] = va1.w;
        Bsf[kc+0][r]    = vb.x;  Bsf[kc+1][r]    = vb.y;  Bsf[kc+2][r]    = vb.z;  Bsf[kc+3][r]    = vb.w;
        __syncthreads();
        #pragma unroll
        for (int k = 0; k < 16; ++k) {
            float a[8], bb[4];
            *(float4*)&a[0] = *(const float4*)&Asf[k][ty*8];
            *(float4*)&a[4] = *(const float4*)&Asf[k][ty*8+4];
            *(float4*)&bb[0] = *(const float4*)&Bsf[k][tx*4];
            #pragma unroll
            for (int ii = 0; ii < 8; ++ii)
                #pragma unroll
                for (int jj = 0; jj < 4; ++jj)
                    acc[ii][jj] = fmaf(a[ii], bb[jj], acc[ii][jj]);
        }
        __syncthreads();
    }
    if (!SPLIT) {
        #pragma unroll
        for (int ii = 0; ii < 8; ++ii) {
            float4 v = make_float4(acc[ii][0], acc[ii][1], acc[ii][2], acc[ii][3]);
            *(float4*)&C[(size_t)(i0 + ty*8 + ii) * ldc + j0 + tx*4] = v;
        }
    } else {
        #pragma unroll
        for (int ii = 0; ii < 8; ++ii)
            #pragma unroll
            for (int jj = 0; jj < 4; ++jj) {
                int col = j0 + tx*4 + jj;
                if (col < Nb)
                    atomicAdd(&C[(size_t)(i0 + ty*8 + ii) * ldc + col], acc[ii][jj]);
            }
    }
}

// causal depthwise conv(16) + bias + SiLU; thread = 4 e's (float4) x 16 l's
__global__ __launch_bounds__(256) void conv_silu(const float* __restrict__ xz,
    const float* __restrict__ Wc, const float* __restrict__ bc, float* __restrict__ xf)
{
    int t  = blockIdx.x * 256 + threadIdx.x;     // 0..65535
    int e4 = (t & 127) * 4;
    int l0 = ((t >> 7) & 63) * 16;
    int b  = t >> 13;
    float4 w[16];
    #pragma unroll
    for (int k = 0; k < 16; ++k)
        w[k] = make_float4(Wc[(e4+0)*16+k], Wc[(e4+1)*16+k], Wc[(e4+2)*16+k], Wc[(e4+3)*16+k]);
    float4 bc4 = *(const float4*)&bc[e4];
    const float* xzb = xz + (size_t)b * L_SZ * 1024 + e4;
    float*       xfb = xf + (size_t)b * L_SZ * ED + e4;
    float4 xw[16];
    #pragma unroll
    for (int j = 1; j <= 15; ++j) {
        int row = l0 - 16 + j;
        xw[j] = (row >= 0) ? *(const float4*)(xzb + (size_t)row * 1024) : make_float4(0.f,0.f,0.f,0.f);
    }
    #pragma unroll
    for (int u = 0; u < 16; ++u) {
        int l = l0 + u;
        xw[u] = *(const float4*)(xzb + (size_t)l * 1024);
        float4 acc = bc4;
        #pragma unroll
        for (int k = 0; k < 16; ++k) {
            float4 xv = xw[(u + k + 1) & 15];
            acc.x = fmaf(xv.x, w[k].x, acc.x);
            acc.y = fmaf(xv.y, w[k].y, acc.y);
            acc.z = fmaf(xv.z, w[k].z, acc.z);
            acc.w = fmaf(xv.w, w[k].w, acc.w);
        }
        float4 o = make_float4(siluf(acc.x), siluf(acc.y), siluf(acc.z), siluf(acc.w));
        *(float4*)(xfb + (size_t)l * ED) = o;
    }
}

// delta[m,e] = softplus(sum_r dBC[m,r]*W_dt[e,r] + b_dt[e])
__global__ __launch_bounds__(256) void delta_kernel(const float* __restrict__ dBC,
    const float* __restrict__ W_dt, const float* __restrict__ b_dt, float* __restrict__ dlt)
{
    const int tid = threadIdx.x;
    const int m0 = blockIdx.x * 32;
    float w0[16], w1[16];
    #pragma unroll
    for (int q = 0; q < 4; ++q) {
        *(float4*)&w0[q*4] = *(const float4*)&W_dt[(size_t)tid*16 + q*4];
        *(float4*)&w1[q*4] = *(const float4*)&W_dt[(size_t)(tid+256)*16 + q*4];
    }
    float bd0 = b_dt[tid], bd1 = b_dt[tid+256];
    for (int m = 0; m < 32; ++m) {
        const float* row = dBC + (size_t)(m0+m)*48;
        float qr[16];
        #pragma unroll
        for (int q = 0; q < 4; ++q) *(float4*)&qr[q*4] = *(const float4*)&row[q*4];
        float s0 = bd0, s1 = bd1;
        #pragma unroll
        for (int rr = 0; rr < 16; ++rr) { s0 = fmaf(qr[rr], w0[rr], s0); s1 = fmaf(qr[rr], w1[rr], s1); }
        dlt[(size_t)(m0+m)*512 + tid]       = softplusf(s0);
        dlt[(size_t)(m0+m)*512 + tid + 256] = softplusf(s1);
    }
}

// ---------- chunked scan ----------
__global__ __launch_bounds__(256) void scan_local(
    const float* __restrict__ dlt, const float* __restrict__ xf,
    const float* __restrict__ dbc, const float* __restrict__ A_log,
    float* __restrict__ hend, float* __restrict__ pprod)
{
    __shared__ float ds_d[16][68];
    __shared__ float ds_x[16][68];
    __shared__ float ds_Bv[16][68];
    const int tid = threadIdx.x;
    const int blk = blockIdx.x;
    const int c  = blk & 15;
    const int eg = (blk >> 4) & 31;
    const int b  = blk >> 9;
    const int e0 = eg << 4;
    const int n  = tid & 15;
    const float An = -__expf(A_log[e0 * 16 + tid]);
    const int el = tid >> 4;
    const size_t rowbase = (size_t)b * 1024 + c * LC;
    #pragma unroll
    for (int s = 0; s < 4; ++s) {
        int idx = tid + s * 256;
        int li = idx >> 4, ei = idx & 15;
        size_t row = rowbase + li;
        ds_d[ei][li]  = dlt[row * 512 + e0 + ei];
        ds_x[ei][li]  = xf [row * 512 + e0 + ei];
        ds_Bv[ei][li] = dbc[row * 48 + 16 + ei];
    }
    __syncthreads();
    float h = 0.f, pd = 1.f;
    for (int li4 = 0; li4 < LC; li4 += 4) {
        float4 dv = *(const float4*)&ds_d[el][li4];
        float4 xv = *(const float4*)&ds_x[el][li4];
        float4 bv = *(const float4*)&ds_Bv[n][li4];
        #pragma unroll
        for (int u = 0; u < 4; ++u) {
            float dd = (&dv.x)[u], xx = (&xv.x)[u], bb = (&bv.x)[u];
            float dA = __expf(dd * An);
            h = fmaf(dA, h, dd * bb * xx);
            pd *= dA;
        }
    }
    size_t o = (size_t)(b * 16 + c) * 8192 + e0 * 16 + tid;
    hend[o]  = h;
    pprod[o] = pd;
}

__global__ __launch_bounds__(256) void scan_prefix(
    const float* __restrict__ hend, const float* __restrict__ pprod, float* __restrict__ hs)
{
    int idx = blockIdx.x * 256 + threadIdx.x;
    int b  = idx >> 13;
    int en = idx & 8191;
    size_t base = (size_t)b * 16 * 8192 + en;
    float h = 0.f;
    #pragma unroll
    for (int c = 0; c < 16; ++c) {
        size_t o = base + (size_t)c * 8192;
        hs[o] = h;
        h = fmaf(pprod[o], h, hend[o]);
    }
}

__global__ __launch_bounds__(256) void scan_emit(
    const float* __restrict__ dlt, const float* __restrict__ xf,
    const float* __restrict__ dbc, const float* __restrict__ A_log,
    const float* __restrict__ D, const float* __restrict__ hs, float* __restrict__ y)
{
    __shared__ float ds_d[16][68];
    __shared__ float ds_x[16][68];
    __shared__ float ds_Bv[16][68];
    __shared__ float ds_Cv[16][68];
    __shared__ float ds_y[16][68];
    const int tid = threadIdx.x;
    const int blk = blockIdx.x;
    const int c  = blk & 15;
    const int eg = (blk >> 4) & 31;
    const int b  = blk >> 9;
    const int e0 = eg << 4;
    const int n  = tid & 15;
    const int el = tid >> 4;
    const float An = -__expf(A_log[e0 * 16 + tid]);
    const float Dv = D[e0 + el];
    const size_t rowbase = (size_t)b * 1024 + c * LC;
    #pragma unroll
    for (int s = 0; s < 4; ++s) {
        int idx = tid + s * 256;
        int li = idx >> 4, ei = idx & 15;
        size_t row = rowbase + li;
        ds_d[ei][li]  = dlt[row * 512 + e0 + ei];
        ds_x[ei][li]  = xf [row * 512 + e0 + ei];
        ds_Bv[ei][li] = dbc[row * 48 + 16 + ei];
        ds_Cv[ei][li] = dbc[row * 48 + 32 + ei];
    }
    float h = hs[(size_t)(b * 16 + c) * 8192 + e0 * 16 + tid];
    __syncthreads();
    for (int li4 = 0; li4 < LC; li4 += 4) {
        float4 dv = *(const float4*)&ds_d[el][li4];
        float4 xv = *(const float4*)&ds_x[el][li4];
        float4 bv = *(const float4*)&ds_Bv[n][li4];
        float4 cv = *(const float4*)&ds_Cv[n][li4];
        float yo[4];
        #pragma unroll
        for (int u = 0; u < 4; ++u) {
            float dd = (&dv.x)[u], xx = (&xv.x)[u], bb = (&bv.x)[u], cc = (&cv.x)[u];
            float dA = __expf(dd * An);
            h = fmaf(dA, h, dd * bb * xx);
            float p = h * cc;
            p = dpp_add<0xB1>(p);
            p = dpp_add<0x4E>(p);
            p = dpp_add<0x141>(p);
            p = dpp_add<0x140>(p);
            yo[u] = fmaf(Dv, xx, p);
        }
        if (n == 0) *(float4*)&ds_y[el][li4] = make_float4(yo[0], yo[1], yo[2], yo[3]);
    }
    __syncthreads();
    #pragma unroll
    for (int s = 0; s < 4; ++s) {
        int idx = tid + s * 256;
        int li = idx >> 4, ei = idx & 15;
        size_t row = rowbase + li;
        y[row * 512 + e0 + ei] = ds_y[ei][li];
    }
}

// g = y*silu(zf) emitted directly as split-bf16 A-side [hi|lo|hi], row stride 1536
__global__ __launch_bounds__(256) void gate_split(const float* __restrict__ y,
    const float* __restrict__ xz, unsigned short* __restrict__ G)
{
    int i  = blockIdx.x * 256 + threadIdx.x;
    int i4 = i * 4;
    int m  = i4 >> 9;
    int e  = i4 & 511;
    float4 yv = *(const float4*)&y[i4];
    float4 zv = *(const float4*)&xz[(size_t)m * 1024 + 512 + e];
    float g0 = yv.x * siluf(zv.x), g1 = yv.y * siluf(zv.y);
    float g2 = yv.z * siluf(zv.z), g3 = yv.w * siluf(zv.w);
    ushort4 hi, lo;
    hi.x = f2bf(g0); lo.x = f2bf(g0 - bf2f(hi.x));
    hi.y = f2bf(g1); lo.y = f2bf(g1 - bf2f(hi.y));
    hi.z = f2bf(g2); lo.z = f2bf(g2 - bf2f(hi.z));
    hi.w = f2bf(g3); lo.w = f2bf(g3 - bf2f(hi.w));
    size_t base = (size_t)m * 1536 + e;
    *(ushort4*)&G[base]        = hi;   // A-side: [hi | lo | hi]
    *(ushort4*)&G[base + 512]  = lo;
    *(ushort4*)&G[base + 1024] = hi;
}

extern "C" void kernel_launch(void* const* d_in, const int* in_sizes, int n_in,
                              void* d_out, int out_size, void* d_ws, size_t ws_size,
                              hipStream_t stream) {
    const float* x      = (const float*)d_in[0];
    const float* W_in   = (const float*)d_in[1];
    const float* W_conv = (const float*)d_in[2];
    const float* b_conv = (const float*)d_in[3];
    const float* W_x    = (const float*)d_in[4];
    const float* W_dt   = (const float*)d_in[5];
    const float* b_dt   = (const float*)d_in[6];
    const float* A_log  = (const float*)d_in[7];
    const float* D      = (const float*)d_in[8];
    const float* W_out  = (const float*)d_in[9];
    float* out = (float*)d_out;

    // ---- workspace layout: identical footprint to round 3 (proven to fit) ----
    float* ws   = (float*)d_ws;
    float* xz   = ws;                              // 8192*1024 f
    float* xf   = xz   + (size_t)M_SZ * 1024;      // 8192*512 f
    float* dbc  = xf   + (size_t)M_SZ * ED;        // 8192*48 f
    float* dlt  = dbc  + (size_t)M_SZ * 48;        // 8192*512 f
    float* yb   = dlt  + (size_t)M_SZ * ED;        // 8192*512 f
    float* hend = yb   + (size_t)M_SZ * ED;        // 1M f
    float* ppr  = hend + (size_t)B_SZ * CH * 8192; // 1M f
    float* hs   = ppr  + (size_t)B_SZ * CH * 8192; // 1M f
    // bf16 buffers aliased into dead fp32 regions:
    unsigned short* Ax = (unsigned short*)dlt;   // 12.6MB in dlt slot (dlt written at step 4; Ax dead by then)
    unsigned short* Wi = (unsigned short*)yb;    // 1.5MB in yb slot (yb written at scan_emit)
    unsigned short* Gp = (unsigned short*)xf;    // 25.2MB spans xf+dbc+dlt-head (dead after scan_emit)
    unsigned short* Wo = (unsigned short*)hend;  // 0.8MB in hend slot (dead after scan_prefix)

    // 1) split x (A-side) and W_in (B-side); xz = x @ W_in^T via bf16 MFMA (K'=768)
    split3<false><<<2048, 256, 0, stream>>>(x, Ax, 8);
    split3<true> <<<256,  256, 0, stream>>>(W_in, Wi, 8);
    gemm_bf16<false><<<dim3(8, 64, 1), 256, 0, stream>>>(Ax, Wi, xz, 768, 768, 1024);
    // 2) xf = silu(causal_conv(xz[:, :512]) + b_conv)
    conv_silu<<<256, 256, 0, stream>>>(xz, W_conv, b_conv, xf);
    // 3) dBC = xf @ W_x^T, fp32 split-K=4
    (void)hipMemsetAsync(dbc, 0, (size_t)M_SZ * 48 * sizeof(float), stream);
    gemm_nt<true><<<dim3(1, 64, 4), 256, 0, stream>>>(xf, W_x, dbc, 128, 512, 512, 48, 48);
    // 4) delta
    delta_kernel<<<256, 256, 0, stream>>>(dbc, W_dt, b_dt, dlt);
    // 5) chunked selective scan
    scan_local <<<4096, 256, 0, stream>>>(dlt, xf, dbc, A_log, hend, ppr);
    scan_prefix<<<256, 256, 0, stream>>>(hend, ppr, hs);
    scan_emit  <<<4096, 256, 0, stream>>>(dlt, xf, dbc, A_log, D, hs, yb);
    // 6) split W_out (B-side, into hend slot); G = (yb*silu(zf)) split-bf16 A-side
    split3<true><<<128, 256, 0, stream>>>(W_out, Wo, 9);
    gate_split<<<4096, 256, 0, stream>>>(yb, xz, Gp);
    // 7) out = G @ Wo^T via bf16 MFMA (K'=1536, split-K=2, atomic)
    (void)hipMemsetAsync(out, 0, (size_t)M_SZ * DM * sizeof(float), stream);
    gemm_bf16<true><<<dim3(2, 64, 2), 256, 0, stream>>>(Gp, Wo, out, 1536, 768, 256);
}

// Round 7
// 261.239 us; speedup vs baseline: 1.6174x; 1.0712x over previous
//
#include <hip/hip_runtime.h>

#define B_SZ 8
#define L_SZ 1024
#define DM   256
#define ED   512
#define M_SZ (B_SZ * L_SZ)   // 8192
#define CH   16              // scan chunks
#define LC   64              // chunk length

typedef __attribute__((ext_vector_type(8))) short short8;
typedef __attribute__((ext_vector_type(4))) float floatx4;

__device__ __forceinline__ float siluf(float x) { return x / (1.f + __expf(-x)); }
__device__ __forceinline__ float softplusf(float x) { return x > 20.f ? x : log1pf(__expf(x)); }

template<int CTRL>
__device__ __forceinline__ float dpp_add(float v) {
    int t = __builtin_amdgcn_update_dpp(0, __float_as_int(v), CTRL, 0xF, 0xF, true);
    return v + __int_as_float(t);
}

__device__ __forceinline__ unsigned short f2bf(float f) {
    unsigned u = __float_as_uint(f);
    u += 0x7FFF + ((u >> 16) & 1);   // RNE
    return (unsigned short)(u >> 16);
}
__device__ __forceinline__ float bf2f(unsigned short h) {
    return __uint_as_float((unsigned)h << 16);
}

__device__ __forceinline__ void glds16(const unsigned short* g, unsigned short* l) {
    __builtin_amdgcn_global_load_lds(
        (const __attribute__((address_space(1))) void*)g,
        (__attribute__((address_space(3))) void*)l, 16, 0, 0);
}

// ---------------- split fp32 -> 3-segment bf16, row stride 3K ----------------
// A-side: [hi | lo | hi]   B-side: [hi | hi | lo]  =>  A'.B' = hi*hi + lo*hi + hi*lo
__device__ __forceinline__ void split_one(const float* __restrict__ S,
    unsigned short* __restrict__ Dst, int Klog2, int i, bool bside)
{
    int i4 = i << 2;
    int K  = 1 << Klog2;
    int row = i4 >> Klog2;
    int k   = i4 & (K - 1);
    float4 v = *(const float4*)&S[i4];
    ushort4 hi, lo;
    float f;
    f = v.x; hi.x = f2bf(f); lo.x = f2bf(f - bf2f(hi.x));
    f = v.y; hi.y = f2bf(f); lo.y = f2bf(f - bf2f(hi.y));
    f = v.z; hi.z = f2bf(f); lo.z = f2bf(f - bf2f(hi.z));
    f = v.w; hi.w = f2bf(f); lo.w = f2bf(f - bf2f(hi.w));
    size_t base = (size_t)row * (3 << Klog2) + k;
    *(ushort4*)&Dst[base] = hi;
    if (bside) {
        *(ushort4*)&Dst[base + K]   = hi;
        *(ushort4*)&Dst[base + 2*K] = lo;
    } else {
        *(ushort4*)&Dst[base + K]   = lo;
        *(ushort4*)&Dst[base + 2*K] = hi;
    }
}

// one kernel splits all three static inputs: x (A-side), W_in (B), W_out (B)
__global__ __launch_bounds__(256) void split_inputs(
    const float* __restrict__ x, const float* __restrict__ W_in, const float* __restrict__ W_out,
    unsigned short* __restrict__ Ax, unsigned short* __restrict__ Wi, unsigned short* __restrict__ Wo)
{
    int bid = blockIdx.x;
    if (bid < 2048)      split_one(x,     Ax,  8, bid * 256 + threadIdx.x, false);
    else if (bid < 2304) split_one(W_in,  Wi,  8, (bid - 2048) * 256 + threadIdx.x, true);
    else                 split_one(W_out, Wo,  9, (bid - 2304) * 256 + threadIdx.x, true);
}

// ---------------- bf16 MFMA GEMM: C[M,N] = A'[M,K3] * B'[N,K3]^T ----------------
template<bool SPLITK>
__global__ __launch_bounds__(256) void gemm_bf16(
    const unsigned short* __restrict__ A, const unsigned short* __restrict__ Bm,
    float* __restrict__ C, int K3, int Klen, int ldc)
{
    __shared__ __align__(16) unsigned short As[128 * 64];
    __shared__ __align__(16) unsigned short Bs[128 * 64];
    const int tid = threadIdx.x;
    const int w  = tid >> 6, ln = tid & 63;
    const int m0 = blockIdx.y * 128, n0 = blockIdx.x * 128;
    const int kbase = SPLITK ? blockIdx.z * Klen : 0;
    const int lm = ln & 15, kg = ln >> 4;
    const int rb = (w >> 1) * 64, cb = (w & 1) * 64;
    floatx4 acc[4][4];
    #pragma unroll
    for (int i = 0; i < 4; ++i)
        #pragma unroll
        for (int j = 0; j < 4; ++j) acc[i][j] = (floatx4)0.f;

    const int srow = ln >> 3;
    const int scol = (ln & 7) * 8;
    const unsigned short* Ag = A  + (size_t)(m0 + w*32 + srow) * K3 + kbase + scol;
    const unsigned short* Bg = Bm + (size_t)(n0 + w*32 + srow) * K3 + kbase + scol;
    unsigned short* Al = &As[(w*32) * 64];
    unsigned short* Bl = &Bs[(w*32) * 64];

    for (int k0 = 0; k0 < Klen; k0 += 64) {
        #pragma unroll
        for (int q = 0; q < 4; ++q) {
            glds16(Ag + (size_t)(q*8) * K3 + k0, Al + (q*8) * 64);
            glds16(Bg + (size_t)(q*8) * K3 + k0, Bl + (q*8) * 64);
        }
        __syncthreads();
        #pragma unroll
        for (int kk = 0; kk < 64; kk += 32) {
            short8 af[4], bfr[4];
            #pragma unroll
            for (int i = 0; i < 4; ++i)
                af[i] = *(const short8*)&As[(rb + i*16 + lm) * 64 + kk + kg*8];
            #pragma unroll
            for (int j = 0; j < 4; ++j)
                bfr[j] = *(const short8*)&Bs[(cb + j*16 + lm) * 64 + kk + kg*8];
            #pragma unroll
            for (int i = 0; i < 4; ++i)
                #pragma unroll
                for (int j = 0; j < 4; ++j)
                    acc[i][j] = __builtin_amdgcn_mfma_f32_16x16x32_bf16(af[i], bfr[j], acc[i][j], 0, 0, 0);
        }
        __syncthreads();
    }
    #pragma unroll
    for (int i = 0; i < 4; ++i)
        #pragma unroll
        for (int j = 0; j < 4; ++j) {
            int row = m0 + rb + i*16 + kg*4;
            int col = n0 + cb + j*16 + lm;
            #pragma unroll
            for (int r = 0; r < 4; ++r) {
                float v = acc[i][j][r];
                if (SPLITK) atomicAdd(&C[(size_t)(row + r) * ldc + col], v);
                else        C[(size_t)(row + r) * ldc + col] = v;
            }
        }
}

// ---------------- fp32 NT GEMM (skinny dBC matmul) ----------------
template<bool SPLIT>
__global__ __launch_bounds__(256) void gemm_nt(const float* __restrict__ A, const float* __restrict__ Bm,
    float* __restrict__ C, int Klen, int lda, int ldb, int ldc, int Nb)
{
    __shared__ float Asf[16][132];
    __shared__ float Bsf[16][68];
    const int tid = threadIdx.x;
    const int i0 = blockIdx.y * 128;
    const int j0 = blockIdx.x * 64;
    const int kbase = SPLIT ? blockIdx.z * Klen : 0;
    const int tx = tid & 15, ty = tid >> 4;
    const int r  = tid >> 2;
    const int kc = (tid & 3) << 2;
    float acc[8][4] = {{0.f}};
    const float* Arow0 = A + (size_t)(i0 + r) * lda + kbase + kc;
    const float* Arow1 = Arow0 + (size_t)64 * lda;
    const float* Brow  = Bm + (size_t)(j0 + r) * ldb + kbase + kc;
    const bool bok = (!SPLIT) || (j0 + r < Nb);
    for (int k0 = 0; k0 < Klen; k0 += 16) {
        float4 va0 = *(const float4*)(Arow0 + k0);
        float4 va1 = *(const float4*)(Arow1 + k0);
        float4 vb  = bok ? *(const float4*)(Brow + k0) : make_float4(0.f,0.f,0.f,0.f);
        Asf[kc+0][r]    = va0.x; Asf[kc+1][r]    = va0.y; Asf[kc+2][r]    = va0.z; Asf[kc+3][r]    = va0.w;
        Asf[kc+0][64+r] = va1.x; Asf[kc+1][64+r] = va1.y; Asf[kc+2][64+r] = va1.z; Asf[kc+3][64+r] = va1.w;
        Bsf[kc+0][r]    = vb.x;  Bsf[kc+1][r]    = vb.y;  Bsf[kc+2][r]    = vb.z;  Bsf[kc+3][r]    = vb.w;
        __syncthreads();
        #pragma unroll
        for (int k = 0; k < 16; ++k) {
            float a[8], bb[4];
            *(float4*)&a[0] = *(const float4*)&Asf[k][ty*8];
            *(float4*)&a[4] = *(const float4*)&Asf[k][ty*8+4];
            *(float4*)&bb[0] = *(const float4*)&Bsf[k][tx*4];
            #pragma unroll
            for (int ii = 0; ii < 8; ++ii)
                #pragma unroll
                for (int jj = 0; jj < 4; ++jj)
                    acc[ii][jj] = fmaf(a[ii], bb[jj], acc[ii][jj]);
        }
        __syncthreads();
    }
    if (!SPLIT) {
        #pragma unroll
        for (int ii = 0; ii < 8; ++ii) {
            float4 v = make_float4(acc[ii][0], acc[ii][1], acc[ii][2], acc[ii][3]);
            *(float4*)&C[(size_t)(i0 + ty*8 + ii) * ldc + j0 + tx*4] = v;
        }
    } else {
        #pragma unroll
        for (int ii = 0; ii < 8; ++ii)
            #pragma unroll
            for (int jj = 0; jj < 4; ++jj) {
                int col = j0 + tx*4 + jj;
                if (col < Nb)
                    atomicAdd(&C[(size_t)(i0 + ty*8 + ii) * ldc + col], acc[ii][jj]);
            }
    }
}

// causal depthwise conv(16) + bias + SiLU
__global__ __launch_bounds__(256) void conv_silu(const float* __restrict__ xz,
    const float* __restrict__ Wc, const float* __restrict__ bc, float* __restrict__ xf)
{
    int t  = blockIdx.x * 256 + threadIdx.x;
    int e4 = (t & 127) * 4;
    int l0 = ((t >> 7) & 63) * 16;
    int b  = t >> 13;
    float4 w[16];
    #pragma unroll
    for (int k = 0; k < 16; ++k)
        w[k] = make_float4(Wc[(e4+0)*16+k], Wc[(e4+1)*16+k], Wc[(e4+2)*16+k], Wc[(e4+3)*16+k]);
    float4 bc4 = *(const float4*)&bc[e4];
    const float* xzb = xz + (size_t)b * L_SZ * 1024 + e4;
    float*       xfb = xf + (size_t)b * L_SZ * ED + e4;
    float4 xw[16];
    #pragma unroll
    for (int j = 1; j <= 15; ++j) {
        int row = l0 - 16 + j;
        xw[j] = (row >= 0) ? *(const float4*)(xzb + (size_t)row * 1024) : make_float4(0.f,0.f,0.f,0.f);
    }
    #pragma unroll
    for (int u = 0; u < 16; ++u) {
        int l = l0 + u;
        xw[u] = *(const float4*)(xzb + (size_t)l * 1024);
        float4 acc = bc4;
        #pragma unroll
        for (int k = 0; k < 16; ++k) {
            float4 xv = xw[(u + k + 1) & 15];
            acc.x = fmaf(xv.x, w[k].x, acc.x);
            acc.y = fmaf(xv.y, w[k].y, acc.y);
            acc.z = fmaf(xv.z, w[k].z, acc.z);
            acc.w = fmaf(xv.w, w[k].w, acc.w);
        }
        float4 o = make_float4(siluf(acc.x), siluf(acc.y), siluf(acc.z), siluf(acc.w));
        *(float4*)(xfb + (size_t)l * ED) = o;
    }
}

// ---------- chunked scan with inline delta ----------
// delta[row, e] = softplus(dot16(dbc[row,0:16], W_dt[e,:]) + b_dt[e]) computed during staging.
__global__ __launch_bounds__(256) void scan_local(
    const float* __restrict__ xf, const float* __restrict__ dbc,
    const float* __restrict__ W_dt, const float* __restrict__ b_dt,
    const float* __restrict__ A_log,
    float* __restrict__ hend, float* __restrict__ pprod)
{
    __shared__ float ds_d[16][68];
    __shared__ float ds_x[16][68];
    __shared__ float ds_Bv[16][68];
    const int tid = threadIdx.x;
    const int blk = blockIdx.x;
    const int c  = blk & 15;
    const int eg = (blk >> 4) & 31;
    const int b  = blk >> 9;
    const int e0 = eg << 4;
    const int n  = tid & 15;
    const int el = tid >> 4;
    const float An = -__expf(A_log[e0 * 16 + tid]);
    const size_t rowbase = (size_t)b * 1024 + c * LC;
    // per-thread delta weights for fixed e = e0 + (tid & 15)
    const int ei = tid & 15;
    float wdt[16];
    #pragma unroll
    for (int q = 0; q < 4; ++q)
        *(float4*)&wdt[q*4] = *(const float4*)&W_dt[(size_t)(e0 + ei) * 16 + q*4];
    const float bd = b_dt[e0 + ei];
    #pragma unroll
    for (int s = 0; s < 4; ++s) {
        int li = (tid >> 4) + 16 * s;
        size_t row = rowbase + li;
        ds_x[ei][li]  = xf [row * 512 + e0 + ei];
        ds_Bv[ei][li] = dbc[row * 48 + 16 + ei];
        float dr[16];
        #pragma unroll
        for (int q = 0; q < 4; ++q) *(float4*)&dr[q*4] = *(const float4*)&dbc[row * 48 + q*4];
        float sdt = bd;
        #pragma unroll
        for (int r = 0; r < 16; ++r) sdt = fmaf(dr[r], wdt[r], sdt);
        ds_d[ei][li] = softplusf(sdt);
    }
    __syncthreads();
    float h = 0.f, pd = 1.f;
    for (int li4 = 0; li4 < LC; li4 += 4) {
        float4 dv = *(const float4*)&ds_d[el][li4];
        float4 xv = *(const float4*)&ds_x[el][li4];
        float4 bv = *(const float4*)&ds_Bv[n][li4];
        #pragma unroll
        for (int u = 0; u < 4; ++u) {
            float dd = (&dv.x)[u], xx = (&xv.x)[u], bb = (&bv.x)[u];
            float dA = __expf(dd * An);
            h = fmaf(dA, h, dd * bb * xx);
            pd *= dA;
        }
    }
    size_t o = (size_t)(b * 16 + c) * 8192 + e0 * 16 + tid;
    hend[o]  = h;
    pprod[o] = pd;
}

__global__ __launch_bounds__(256) void scan_prefix(
    const float* __restrict__ hend, const float* __restrict__ pprod, float* __restrict__ hs)
{
    int idx = blockIdx.x * 256 + threadIdx.x;
    int b  = idx >> 13;
    int en = idx & 8191;
    size_t base = (size_t)b * 16 * 8192 + en;
    float h = 0.f;
    #pragma unroll
    for (int c = 0; c < 16; ++c) {
        size_t o = base + (size_t)c * 8192;
        hs[o] = h;
        h = fmaf(pprod[o], h, hend[o]);
    }
}

// pass 3: re-scan from hs, emit g = (y + D*xf)*silu(zf) directly as split-bf16 A-side [hi|lo|hi]
__global__ __launch_bounds__(256) void scan_emit_gate(
    const float* __restrict__ xf, const float* __restrict__ dbc,
    const float* __restrict__ W_dt, const float* __restrict__ b_dt,
    const float* __restrict__ A_log, const float* __restrict__ D,
    const float* __restrict__ hs, const float* __restrict__ xz,
    unsigned short* __restrict__ G)
{
    __shared__ float ds_d[16][68];
    __shared__ float ds_x[16][68];
    __shared__ float ds_Bv[16][68];
    __shared__ float ds_Cv[16][68];
    __shared__ float ds_y[16][68];
    const int tid = threadIdx.x;
    const int blk = blockIdx.x;
    const int c  = blk & 15;
    const int eg = (blk >> 4) & 31;
    const int b  = blk >> 9;
    const int e0 = eg << 4;
    const int n  = tid & 15;
    const int el = tid >> 4;
    const float An = -__expf(A_log[e0 * 16 + tid]);
    const float Dv = D[e0 + el];
    const size_t rowbase = (size_t)b * 1024 + c * LC;
    const int ei = tid & 15;
    float wdt[16];
    #pragma unroll
    for (int q = 0; q < 4; ++q)
        *(float4*)&wdt[q*4] = *(const float4*)&W_dt[(size_t)(e0 + ei) * 16 + q*4];
    const float bd = b_dt[e0 + ei];
    #pragma unroll
    for (int s = 0; s < 4; ++s) {
        int li = (tid >> 4) + 16 * s;
        size_t row = rowbase + li;
        ds_x[ei][li]  = xf [row * 512 + e0 + ei];
        ds_Bv[ei][li] = dbc[row * 48 + 16 + ei];
        ds_Cv[ei][li] = dbc[row * 48 + 32 + ei];
        float dr[16];
        #pragma unroll
        for (int q = 0; q < 4; ++q) *(float4*)&dr[q*4] = *(const float4*)&dbc[row * 48 + q*4];
        float sdt = bd;
        #pragma unroll
        for (int r = 0; r < 16; ++r) sdt = fmaf(dr[r], wdt[r], sdt);
        ds_d[ei][li] = softplusf(sdt);
    }
    float h = hs[(size_t)(b * 16 + c) * 8192 + e0 * 16 + tid];
    __syncthreads();
    for (int li4 = 0; li4 < LC; li4 += 4) {
        float4 dv = *(const float4*)&ds_d[el][li4];
        float4 xv = *(const float4*)&ds_x[el][li4];
        float4 bv = *(const float4*)&ds_Bv[n][li4];
        float4 cv = *(const float4*)&ds_Cv[n][li4];
        float yo[4];
        #pragma unroll
        for (int u = 0; u < 4; ++u) {
            float dd = (&dv.x)[u], xx = (&xv.x)[u], bb = (&bv.x)[u], cc = (&cv.x)[u];
            float dA = __expf(dd * An);
            h = fmaf(dA, h, dd * bb * xx);
            float p = h * cc;
            p = dpp_add<0xB1>(p);
            p = dpp_add<0x4E>(p);
            p = dpp_add<0x141>(p);
            p = dpp_add<0x140>(p);
            yo[u] = fmaf(Dv, xx, p);
        }
        if (n == 0) *(float4*)&ds_y[el][li4] = make_float4(yo[0], yo[1], yo[2], yo[3]);
    }
    __syncthreads();
    #pragma unroll
    for (int s = 0; s < 4; ++s) {
        int li = (tid >> 4) + 16 * s;
        size_t row = rowbase + li;
        float yv = ds_y[ei][li];
        float zv = xz[row * 1024 + 512 + e0 + ei];
        float g  = yv * siluf(zv);
        unsigned short hi = f2bf(g);
        unsigned short lo = f2bf(g - bf2f(hi));
        size_t gb = row * 1536 + e0 + ei;
        G[gb]        = hi;
        G[gb + 512]  = lo;
        G[gb + 1024] = hi;
    }
}

extern "C" void kernel_launch(void* const* d_in, const int* in_sizes, int n_in,
                              void* d_out, int out_size, void* d_ws, size_t ws_size,
                              hipStream_t stream) {
    const float* x      = (const float*)d_in[0];
    const float* W_in   = (const float*)d_in[1];
    const float* W_conv = (const float*)d_in[2];
    const float* b_conv = (const float*)d_in[3];
    const float* W_x    = (const float*)d_in[4];
    const float* W_dt   = (const float*)d_in[5];
    const float* b_dt   = (const float*)d_in[6];
    const float* A_log  = (const float*)d_in[7];
    const float* D      = (const float*)d_in[8];
    const float* W_out  = (const float*)d_in[9];
    float* out = (float*)d_out;

    // flat layout, ~105 MB of the 256 MiB workspace
    float* ws   = (float*)d_ws;
    float* xz   = ws;                              // 8192*1024 f
    float* xf   = xz   + (size_t)M_SZ * 1024;      // 8192*512 f
    float* dbc  = xf   + (size_t)M_SZ * ED;        // 8192*48 f
    float* hend = dbc  + (size_t)M_SZ * 48;        // 1M f
    float* ppr  = hend + (size_t)B_SZ * CH * 8192; // 1M f
    float* hs   = ppr  + (size_t)B_SZ * CH * 8192; // 1M f
    unsigned short* Ax = (unsigned short*)(hs + (size_t)B_SZ * CH * 8192); // 8192*768 sh
    unsigned short* Wi = Ax + (size_t)M_SZ * 768;   // 1024*768 sh
    unsigned short* Wo = Wi + (size_t)1024 * 768;   // 256*1536 sh
    unsigned short* Gp = Wo + (size_t)256 * 1536;   // 8192*1536 sh

    // 1) split x/W_in/W_out in one launch
    split_inputs<<<2432, 256, 0, stream>>>(x, W_in, W_out, Ax, Wi, Wo);
    // 2) xz = x @ W_in^T via bf16 MFMA (K'=768)
    gemm_bf16<false><<<dim3(8, 64, 1), 256, 0, stream>>>(Ax, Wi, xz, 768, 768, 1024);
    // 3) xf = silu(causal_conv(xz[:, :512]) + b_conv)
    conv_silu<<<256, 256, 0, stream>>>(xz, W_conv, b_conv, xf);
    // 4) dBC = xf @ W_x^T, fp32 split-K=4
    (void)hipMemsetAsync(dbc, 0, (size_t)M_SZ * 48 * sizeof(float), stream);
    gemm_nt<true><<<dim3(1, 64, 4), 256, 0, stream>>>(xf, W_x, dbc, 128, 512, 512, 48, 48);
    // 5) chunked selective scan (delta inline); emit fused gate+split
    scan_local <<<4096, 256, 0, stream>>>(xf, dbc, W_dt, b_dt, A_log, hend, ppr);
    scan_prefix<<<256, 256, 0, stream>>>(hend, ppr, hs);
    scan_emit_gate<<<4096, 256, 0, stream>>>(xf, dbc, W_dt, b_dt, A_log, D, hs, xz, Gp);
    // 6) out = G @ Wo^T via bf16 MFMA (K'=1536, split-K=2, atomic)
    (void)hipMemsetAsync(out, 0, (size_t)M_SZ * DM * sizeof(float), stream);
    gemm_bf16<true><<<dim3(2, 64, 2), 256, 0, stream>>>(Gp, Wo, out, 1536, 768, 256);
}